// Round 1
// baseline (207.453 us; speedup 1.0000x reference)
//
#include <hip/hip_runtime.h>

#define NB 8
#define CH 128
#define HV 64
#define WV 64
#define HO 128
#define WO 128
#define KK 9
#define CCH 8            // channels staged per phase-2 iteration
#define THREADS 128
// out tile: 16 (ho) x 16 (wo) per block -> value tile 8x8, halo 10x10
// thread owns out pair (ho, wo),(ho, wo+1): tlwp = wo-pair 0..7, tho = 0..15

__global__ __launch_bounds__(THREADS)
void la_fused(const float* __restrict__ guide,   // [8,128,128,128]
              const float* __restrict__ value,   // [8,128,64,64]
              const float* __restrict__ wconv,   // [9,128]
              const float* __restrict__ bconv,   // [9]
              float* __restrict__ out)           // [8,128,128,128]
{
    __shared__ float s_wT[CH * 12];       // transposed weights, row pad 12 (16B-aligned rows)
    __shared__ float s_halo[CCH * 110];   // 8 channels x 10 rows x stride 11

    const int tid = threadIdx.x;
    const int blk = blockIdx.x;
    const int wt = blk & 7;               // wo tile 0..7
    const int ht = (blk >> 3) & 7;        // ho tile 0..7
    const int b  = blk >> 6;              // 0..7

    // stage weights transposed: s_wT[c*12 + k] = wconv[k*128 + c]
    for (int i = tid; i < KK * CH; i += THREADS) {
        int k = i >> 7;
        int c = i & 127;
        s_wT[c * 12 + k] = wconv[i];
    }

    const int tlwp = tid & 7;             // wo-pair index 0..7
    const int tho  = tid >> 3;            // 0..15
    const int ho = ht * 16 + tho;
    const int wo = wt * 16 + tlwp * 2;

    const float* gpix = guide + (((size_t)b * CH) * HO + ho) * WO + wo;

    // ---- phase 1: attention logits (1x1 conv + bias + residual) ----
    float att0[KK], att1[KK];
    #pragma unroll
    for (int k = 0; k < KK; ++k) {
        float2 g = *(const float2*)(gpix + (size_t)k * (HO * WO));
        float bc = bconv[k];
        att0[k] = bc + g.x;
        att1[k] = bc + g.y;
    }
    __syncthreads();   // s_wT ready

    #pragma unroll 4
    for (int c = 0; c < CH; ++c) {
        float2 g = *(const float2*)(gpix + (size_t)c * (HO * WO));
        const float4* wt4 = (const float4*)&s_wT[c * 12];
        float4 wa = wt4[0];
        float4 wb = wt4[1];
        float w8 = s_wT[c * 12 + 8];
        att0[0] += g.x * wa.x;  att1[0] += g.y * wa.x;
        att0[1] += g.x * wa.y;  att1[1] += g.y * wa.y;
        att0[2] += g.x * wa.z;  att1[2] += g.y * wa.z;
        att0[3] += g.x * wa.w;  att1[3] += g.y * wa.w;
        att0[4] += g.x * wb.x;  att1[4] += g.y * wb.x;
        att0[5] += g.x * wb.y;  att1[5] += g.y * wb.y;
        att0[6] += g.x * wb.z;  att1[6] += g.y * wb.z;
        att0[7] += g.x * wb.w;  att1[7] += g.y * wb.w;
        att0[8] += g.x * w8;    att1[8] += g.y * w8;
    }

    // ---- softmax over k (9) for both pixels ----
    {
        float m0 = att0[0], m1 = att1[0];
        #pragma unroll
        for (int k = 1; k < KK; ++k) { m0 = fmaxf(m0, att0[k]); m1 = fmaxf(m1, att1[k]); }
        float s0 = 0.f, s1 = 0.f;
        #pragma unroll
        for (int k = 0; k < KK; ++k) {
            att0[k] = __expf(att0[k] - m0); s0 += att0[k];
            att1[k] = __expf(att1[k] - m1); s1 += att1[k];
        }
        float r0 = 1.0f / s0, r1 = 1.0f / s1;
        #pragma unroll
        for (int k = 0; k < KK; ++k) { att0[k] *= r0; att1[k] *= r1; }
    }

    // ---- phase 2: weighted 3x3 gather over value, loop channels ----
    const int h0 = ht * 8 - 1;            // halo origin (value coords, clamped at load)
    const int w0 = wt * 8 - 1;
    const int lh = tho >> 1;              // local value row 0..7
    const float* vb = value + (size_t)b * CH * (HV * WV);
    float* ob = out + (((size_t)b * CH) * HO + ho) * WO + wo;

    for (int c0 = 0; c0 < CH; c0 += CCH) {
        __syncthreads();                  // protect s_halo from previous iteration's readers
        for (int i = tid; i < CCH * 100; i += THREADS) {
            int cc = i / 100;
            int r  = i - cc * 100;
            int hr = r / 10;
            int wr = r - hr * 10;
            int hh = min(max(h0 + hr, 0), HV - 1);
            int ww = min(max(w0 + wr, 0), WV - 1);
            s_halo[cc * 110 + hr * 11 + wr] =
                vb[(size_t)(c0 + cc) * (HV * WV) + hh * WV + ww];
        }
        __syncthreads();
        #pragma unroll
        for (int cc = 0; cc < CCH; ++cc) {
            const float* hp = &s_halo[cc * 110 + lh * 11 + tlwp];
            float v, r0, r1;
            v = hp[0];  r0  = v * att0[0]; r1  = v * att1[0];
            v = hp[1];  r0 += v * att0[1]; r1 += v * att1[1];
            v = hp[2];  r0 += v * att0[2]; r1 += v * att1[2];
            v = hp[11]; r0 += v * att0[3]; r1 += v * att1[3];
            v = hp[12]; r0 += v * att0[4]; r1 += v * att1[4];
            v = hp[13]; r0 += v * att0[5]; r1 += v * att1[5];
            v = hp[22]; r0 += v * att0[6]; r1 += v * att1[6];
            v = hp[23]; r0 += v * att0[7]; r1 += v * att1[7];
            v = hp[24]; r0 += v * att0[8]; r1 += v * att1[8];
            float2 rr; rr.x = r0; rr.y = r1;
            *(float2*)(ob + (size_t)(c0 + cc) * (HO * WO)) = rr;
        }
    }
}

extern "C" void kernel_launch(void* const* d_in, const int* in_sizes, int n_in,
                              void* d_out, int out_size, void* d_ws, size_t ws_size,
                              hipStream_t stream) {
    const float* guide = (const float*)d_in[0];
    const float* value = (const float*)d_in[1];
    const float* wconv = (const float*)d_in[2];
    const float* bconv = (const float*)d_in[3];
    float* outp = (float*)d_out;
    (void)in_sizes; (void)n_in; (void)out_size; (void)d_ws; (void)ws_size;

    dim3 grid(NB * 8 * 8);   // 512 blocks: b x (ho tiles 8) x (wo tiles 8)
    dim3 block(THREADS);
    la_fused<<<grid, block, 0, stream>>>(guide, value, wconv, bconv, outp);
}

// Round 2
// 167.877 us; speedup vs baseline: 1.2357x; 1.2357x over previous
//
#include <hip/hip_runtime.h>

#define NB 8
#define CH 128
#define HV 64
#define WV 64
#define HO 128
#define WO 128
#define KK 9
#define CCH 8            // channels per gather block

// ======================= kernel A: attention (softmax) =======================
// thread = horizontal out-pixel pair; 256 blocks x 256 threads = 65536 pairs
__global__ __launch_bounds__(256)
void la_att(const float* __restrict__ guide,   // [8,128,128,128]
            const float* __restrict__ wconv,   // [9,128]
            const float* __restrict__ bconv,   // [9]
            float* __restrict__ att)           // [8,9,128,128] (workspace)
{
    __shared__ float s_wT[CH * 12];  // transposed weights, row stride 12 (16B rows)
    const int tid = threadIdx.x;
    for (int i = tid; i < KK * CH; i += 256) {
        int k = i >> 7;
        int c = i & 127;
        s_wT[c * 12 + k] = wconv[i];
    }

    const int gp = blockIdx.x * 256 + tid;   // pair index 0..65535
    const int wo = (gp & 63) * 2;
    const int ho = (gp >> 6) & 127;
    const int b  = gp >> 13;

    const float* gpix = guide + (((size_t)b * CH) * HO + ho) * WO + wo;

    float att0[KK], att1[KK];
    #pragma unroll
    for (int k = 0; k < KK; ++k) {
        float2 g = *(const float2*)(gpix + (size_t)k * (HO * WO));
        float bc = bconv[k];
        att0[k] = bc + g.x;
        att1[k] = bc + g.y;
    }
    __syncthreads();

    #pragma unroll 8
    for (int c = 0; c < CH; ++c) {
        float2 g = *(const float2*)(gpix + (size_t)c * (HO * WO));
        const float4* wt4 = (const float4*)&s_wT[c * 12];
        float4 wa = wt4[0];
        float4 wb = wt4[1];
        float w8 = s_wT[c * 12 + 8];
        att0[0] += g.x * wa.x;  att1[0] += g.y * wa.x;
        att0[1] += g.x * wa.y;  att1[1] += g.y * wa.y;
        att0[2] += g.x * wa.z;  att1[2] += g.y * wa.z;
        att0[3] += g.x * wa.w;  att1[3] += g.y * wa.w;
        att0[4] += g.x * wb.x;  att1[4] += g.y * wb.x;
        att0[5] += g.x * wb.y;  att1[5] += g.y * wb.y;
        att0[6] += g.x * wb.z;  att1[6] += g.y * wb.z;
        att0[7] += g.x * wb.w;  att1[7] += g.y * wb.w;
        att0[8] += g.x * w8;    att1[8] += g.y * w8;
    }

    // softmax over k
    float m0 = att0[0], m1 = att1[0];
    #pragma unroll
    for (int k = 1; k < KK; ++k) { m0 = fmaxf(m0, att0[k]); m1 = fmaxf(m1, att1[k]); }
    float s0 = 0.f, s1 = 0.f;
    #pragma unroll
    for (int k = 0; k < KK; ++k) {
        att0[k] = __expf(att0[k] - m0); s0 += att0[k];
        att1[k] = __expf(att1[k] - m1); s1 += att1[k];
    }
    float r0 = 1.0f / s0, r1 = 1.0f / s1;

    float* apix = att + (((size_t)b * KK) * HO + ho) * WO + wo;
    #pragma unroll
    for (int k = 0; k < KK; ++k) {
        float2 rr; rr.x = att0[k] * r0; rr.y = att1[k] * r1;
        *(float2*)(apix + (size_t)k * (HO * WO)) = rr;
    }
}

// ======================= kernel B: weighted 3x3 gather =======================
// block = (b, channel-group of 8, 16x16 out tile); 8192 blocks x 128 threads
__global__ __launch_bounds__(128)
void la_gather(const float* __restrict__ value,  // [8,128,64,64]
               const float* __restrict__ att,    // [8,9,128,128]
               float* __restrict__ out)          // [8,128,128,128]
{
    __shared__ float s_halo[CCH * 110];   // 8 ch x 10 rows x stride 11

    const int tid = threadIdx.x;
    const int blk = blockIdx.x;
    const int wt = blk & 7;
    const int ht = (blk >> 3) & 7;
    const int cg = (blk >> 6) & 15;
    const int b  = blk >> 10;

    const int tlwp = tid & 7;
    const int tho  = tid >> 3;
    const int ho = ht * 16 + tho;
    const int wo = wt * 16 + tlwp * 2;

    // att load (independent of halo staging — overlaps)
    const float* apix = att + (((size_t)b * KK) * HO + ho) * WO + wo;
    float att0[KK], att1[KK];
    #pragma unroll
    for (int k = 0; k < KK; ++k) {
        float2 a = *(const float2*)(apix + (size_t)k * (HO * WO));
        att0[k] = a.x; att1[k] = a.y;
    }

    // stage 8-channel 10x10 clamped halo
    const int c0 = cg * CCH;
    const int h0 = ht * 8 - 1;
    const int w0 = wt * 8 - 1;
    const float* vb = value + (size_t)b * CH * (HV * WV);
    for (int i = tid; i < CCH * 100; i += 128) {
        int cc = i / 100;
        int r  = i - cc * 100;
        int hr = r / 10;
        int wr = r - hr * 10;
        int hh = min(max(h0 + hr, 0), HV - 1);
        int ww = min(max(w0 + wr, 0), WV - 1);
        s_halo[cc * 110 + hr * 11 + wr] =
            vb[(size_t)(c0 + cc) * (HV * WV) + hh * WV + ww];
    }
    __syncthreads();

    const int lh = tho >> 1;
    float* ob = out + (((size_t)b * CH + c0) * HO + ho) * WO + wo;
    #pragma unroll
    for (int cc = 0; cc < CCH; ++cc) {
        const float* hp = &s_halo[cc * 110 + lh * 11 + tlwp];
        float v, r0, r1;
        v = hp[0];  r0  = v * att0[0]; r1  = v * att1[0];
        v = hp[1];  r0 += v * att0[1]; r1 += v * att1[1];
        v = hp[2];  r0 += v * att0[2]; r1 += v * att1[2];
        v = hp[11]; r0 += v * att0[3]; r1 += v * att1[3];
        v = hp[12]; r0 += v * att0[4]; r1 += v * att1[4];
        v = hp[13]; r0 += v * att0[5]; r1 += v * att1[5];
        v = hp[22]; r0 += v * att0[6]; r1 += v * att1[6];
        v = hp[23]; r0 += v * att0[7]; r1 += v * att1[7];
        v = hp[24]; r0 += v * att0[8]; r1 += v * att1[8];
        float2 rr; rr.x = r0; rr.y = r1;
        *(float2*)(ob + (size_t)cc * (HO * WO)) = rr;
    }
}

// ================== fallback: proven single fused kernel (R1) ==================
__global__ __launch_bounds__(128)
void la_fused(const float* __restrict__ guide,
              const float* __restrict__ value,
              const float* __restrict__ wconv,
              const float* __restrict__ bconv,
              float* __restrict__ out)
{
    __shared__ float s_wT[CH * 12];
    __shared__ float s_halo[CCH * 110];

    const int tid = threadIdx.x;
    const int blk = blockIdx.x;
    const int wt = blk & 7;
    const int ht = (blk >> 3) & 7;
    const int b  = blk >> 6;

    for (int i = tid; i < KK * CH; i += 128) {
        int k = i >> 7;
        int c = i & 127;
        s_wT[c * 12 + k] = wconv[i];
    }

    const int tlwp = tid & 7;
    const int tho  = tid >> 3;
    const int ho = ht * 16 + tho;
    const int wo = wt * 16 + tlwp * 2;

    const float* gpix = guide + (((size_t)b * CH) * HO + ho) * WO + wo;

    float att0[KK], att1[KK];
    #pragma unroll
    for (int k = 0; k < KK; ++k) {
        float2 g = *(const float2*)(gpix + (size_t)k * (HO * WO));
        float bc = bconv[k];
        att0[k] = bc + g.x;
        att1[k] = bc + g.y;
    }
    __syncthreads();

    #pragma unroll 4
    for (int c = 0; c < CH; ++c) {
        float2 g = *(const float2*)(gpix + (size_t)c * (HO * WO));
        const float4* wt4 = (const float4*)&s_wT[c * 12];
        float4 wa = wt4[0];
        float4 wb = wt4[1];
        float w8 = s_wT[c * 12 + 8];
        att0[0] += g.x * wa.x;  att1[0] += g.y * wa.x;
        att0[1] += g.x * wa.y;  att1[1] += g.y * wa.y;
        att0[2] += g.x * wa.z;  att1[2] += g.y * wa.z;
        att0[3] += g.x * wa.w;  att1[3] += g.y * wa.w;
        att0[4] += g.x * wb.x;  att1[4] += g.y * wb.x;
        att0[5] += g.x * wb.y;  att1[5] += g.y * wb.y;
        att0[6] += g.x * wb.z;  att1[6] += g.y * wb.z;
        att0[7] += g.x * wb.w;  att1[7] += g.y * wb.w;
        att0[8] += g.x * w8;    att1[8] += g.y * w8;
    }

    float m0 = att0[0], m1 = att1[0];
    #pragma unroll
    for (int k = 1; k < KK; ++k) { m0 = fmaxf(m0, att0[k]); m1 = fmaxf(m1, att1[k]); }
    float s0 = 0.f, s1 = 0.f;
    #pragma unroll
    for (int k = 0; k < KK; ++k) {
        att0[k] = __expf(att0[k] - m0); s0 += att0[k];
        att1[k] = __expf(att1[k] - m1); s1 += att1[k];
    }
    float r0 = 1.0f / s0, r1 = 1.0f / s1;
    #pragma unroll
    for (int k = 0; k < KK; ++k) { att0[k] *= r0; att1[k] *= r1; }

    const int h0 = ht * 8 - 1;
    const int w0 = wt * 8 - 1;
    const int lh = tho >> 1;
    const float* vb = value + (size_t)b * CH * (HV * WV);
    float* ob = out + (((size_t)b * CH) * HO + ho) * WO + wo;

    for (int c0 = 0; c0 < CH; c0 += CCH) {
        __syncthreads();
        for (int i = tid; i < CCH * 100; i += 128) {
            int cc = i / 100;
            int r  = i - cc * 100;
            int hr = r / 10;
            int wr = r - hr * 10;
            int hh = min(max(h0 + hr, 0), HV - 1);
            int ww = min(max(w0 + wr, 0), WV - 1);
            s_halo[cc * 110 + hr * 11 + wr] =
                vb[(size_t)(c0 + cc) * (HV * WV) + hh * WV + ww];
        }
        __syncthreads();
        #pragma unroll
        for (int cc = 0; cc < CCH; ++cc) {
            const float* hp = &s_halo[cc * 110 + lh * 11 + tlwp];
            float v, r0_, r1_;
            v = hp[0];  r0_  = v * att0[0]; r1_  = v * att1[0];
            v = hp[1];  r0_ += v * att0[1]; r1_ += v * att1[1];
            v = hp[2];  r0_ += v * att0[2]; r1_ += v * att1[2];
            v = hp[11]; r0_ += v * att0[3]; r1_ += v * att1[3];
            v = hp[12]; r0_ += v * att0[4]; r1_ += v * att1[4];
            v = hp[13]; r0_ += v * att0[5]; r1_ += v * att1[5];
            v = hp[22]; r0_ += v * att0[6]; r1_ += v * att1[6];
            v = hp[23]; r0_ += v * att0[7]; r1_ += v * att1[7];
            v = hp[24]; r0_ += v * att0[8]; r1_ += v * att1[8];
            float2 rr; rr.x = r0_; rr.y = r1_;
            *(float2*)(ob + (size_t)(c0 + cc) * (HO * WO)) = rr;
        }
    }
}

extern "C" void kernel_launch(void* const* d_in, const int* in_sizes, int n_in,
                              void* d_out, int out_size, void* d_ws, size_t ws_size,
                              hipStream_t stream) {
    const float* guide = (const float*)d_in[0];
    const float* value = (const float*)d_in[1];
    const float* wconv = (const float*)d_in[2];
    const float* bconv = (const float*)d_in[3];
    float* outp = (float*)d_out;
    (void)in_sizes; (void)n_in; (void)out_size;

    const size_t att_bytes = (size_t)NB * KK * HO * WO * sizeof(float);  // 4.72 MB
    if (ws_size >= att_bytes) {
        float* attp = (float*)d_ws;
        la_att<<<dim3(256), dim3(256), 0, stream>>>(guide, wconv, bconv, attp);
        la_gather<<<dim3(NB * 16 * 64), dim3(128), 0, stream>>>(value, attp, outp);
    } else {
        la_fused<<<dim3(NB * 8 * 8), dim3(128), 0, stream>>>(guide, value, wconv, bconv, outp);
    }
}

// Round 5
// 150.020 us; speedup vs baseline: 1.3828x; 1.1190x over previous
//
#include <hip/hip_runtime.h>

#define NB 8
#define CH 128
#define HV 64
#define WV 64
#define HO 128
#define WO 128
#define KK 9

// ======================= kernel A: attention (softmax) =======================
// 1 out-pixel per thread; 512 blocks x 256 threads = 131072 threads = 2048 waves
__global__ __launch_bounds__(256)
void la_att(const float* __restrict__ guide,   // [8,128,128,128]
            const float* __restrict__ wconv,   // [9,128]
            const float* __restrict__ bconv,   // [9]
            float* __restrict__ att)           // [8,9,128,128] (workspace)
{
    __shared__ float s_wT[CH * 12];  // transposed weights, row stride 12 (16B rows)
    const int tid = threadIdx.x;
    for (int i = tid; i < KK * CH; i += 256) {
        int k = i >> 7;
        int c = i & 127;
        s_wT[c * 12 + k] = wconv[i];
    }

    const int p  = blockIdx.x * 256 + tid;   // pixel index over (b, ho, wo)
    const int wo = p & 127;
    const int ho = (p >> 7) & 127;
    const int b  = p >> 14;

    const float* gpix = guide + ((size_t)b * CH) * (HO * WO) + ho * WO + wo;

    float a[KK];
    #pragma unroll
    for (int k = 0; k < KK; ++k)
        a[k] = bconv[k] + gpix[(size_t)k * (HO * WO)];
    __syncthreads();

    #pragma unroll 8
    for (int c = 0; c < CH; ++c) {
        float g = gpix[(size_t)c * (HO * WO)];
        const float4* w4 = (const float4*)&s_wT[c * 12];
        float4 wa = w4[0];
        float4 wb = w4[1];
        float w8 = s_wT[c * 12 + 8];
        a[0] += g * wa.x;
        a[1] += g * wa.y;
        a[2] += g * wa.z;
        a[3] += g * wa.w;
        a[4] += g * wb.x;
        a[5] += g * wb.y;
        a[6] += g * wb.z;
        a[7] += g * wb.w;
        a[8] += g * w8;
    }

    float m = a[0];
    #pragma unroll
    for (int k = 1; k < KK; ++k) m = fmaxf(m, a[k]);
    float s = 0.f;
    #pragma unroll
    for (int k = 0; k < KK; ++k) { a[k] = __expf(a[k] - m); s += a[k]; }
    float r = 1.0f / s;

    float* apix = att + ((size_t)b * KK) * (HO * WO) + ho * WO + wo;
    #pragma unroll
    for (int k = 0; k < KK; ++k)
        apix[(size_t)k * (HO * WO)] = a[k] * r;
}

// ======================= kernel B: weighted 3x3 gather =======================
// block = (b, 16-channel group, 16(ho) x 32(wo) out tile); 2048 blocks x 128 thr
// thread owns out quad (ho, wo..wo+3) -> float4 stores
// value tile 8x16, halo 10x18 staged per 8 channels, double-buffered (stride 19)
#define HS 190               // 10 * 19 per channel
__global__ __launch_bounds__(128, 4)
void la_gather(const float* __restrict__ value,  // [8,128,64,64]
               const float* __restrict__ att,    // [8,9,128,128]
               float* __restrict__ out)          // [8,128,128,128]
{
    __shared__ float s_halo[2][8 * HS];

    const int tid = threadIdx.x;
    const int blk = blockIdx.x;
    const int wt = blk & 3;               // wo tile (32 wide): 0..3
    const int ht = (blk >> 2) & 7;        // ho tile (16 tall): 0..7
    const int cg = (blk >> 5) & 7;        // channel group of 16: 0..7
    const int b  = blk >> 8;

    const int tlw = tid & 7;              // wo-quad 0..7
    const int tho = tid >> 3;             // 0..15
    const int ho = ht * 16 + tho;
    const int wo = wt * 32 + tlw * 4;

    // ---- att for 4 pixels (float4 per k), independent of staging ----
    const float* apix = att + ((size_t)b * KK) * (HO * WO) + ho * WO + wo;
    float a0[KK], a1[KK], a2[KK], a3[KK];
    #pragma unroll
    for (int k = 0; k < KK; ++k) {
        float4 av = *(const float4*)(apix + (size_t)k * (HO * WO));
        a0[k] = av.x; a1[k] = av.y; a2[k] = av.z; a3[k] = av.w;
    }

    const int c0 = cg * 16;
    const int h0 = ht * 8 - 1;            // halo origin (value coords)
    const int w0 = wt * 16 - 1;
    const float* vb = value + (size_t)b * CH * (HV * WV);

    // stage 8 channels (group g) into buffer bf
    auto stage = [&](int g, int bf) {
        const float* vc = vb + (size_t)(c0 + g * 8) * (HV * WV);
        for (int i = tid; i < 8 * 180; i += 128) {
            int cc = i / 180;
            int r  = i - cc * 180;
            int hr = r / 18;
            int wr = r - hr * 18;
            int hh = min(max(h0 + hr, 0), HV - 1);
            int ww = min(max(w0 + wr, 0), WV - 1);
            s_halo[bf][cc * HS + hr * 19 + wr] =
                vc[(size_t)cc * (HV * WV) + hh * WV + ww];
        }
    };

    stage(0, 0);

    const int lh = tho >> 1;              // local value row 0..7 (halo row lh..lh+2)
    const int lw = tlw * 2;               // local halo col base
    float* ob = out + (((size_t)b * CH + c0) * HO + ho) * WO + wo;

    #pragma unroll
    for (int g = 0; g < 2; ++g) {
        __syncthreads();
        if (g == 0) stage(1, 1);          // loads overlap compute of group 0
        const float* buf = s_halo[g];
        #pragma unroll
        for (int cc = 0; cc < 8; ++cc) {
            const float* hp = &buf[cc * HS + lh * 19 + lw];
            float v00 = hp[0],  v01 = hp[1],  v02 = hp[2],  v03 = hp[3];
            float v10 = hp[19], v11 = hp[20], v12 = hp[21], v13 = hp[22];
            float v20 = hp[38], v21 = hp[39], v22 = hp[40], v23 = hp[41];
            float r0 = v00*a0[0] + v01*a0[1] + v02*a0[2]
                     + v10*a0[3] + v11*a0[4] + v12*a0[5]
                     + v20*a0[6] + v21*a0[7] + v22*a0[8];
            float r1 = v00*a1[0] + v01*a1[1] + v02*a1[2]
                     + v10*a1[3] + v11*a1[4] + v12*a1[5]
                     + v20*a1[6] + v21*a1[7] + v22*a1[8];
            float r2 = v01*a2[0] + v02*a2[1] + v03*a2[2]
                     + v11*a2[3] + v12*a2[4] + v13*a2[5]
                     + v21*a2[6] + v22*a2[7] + v23*a2[8];
            float r3 = v01*a3[0] + v02*a3[1] + v03*a3[2]
                     + v11*a3[3] + v12*a3[4] + v13*a3[5]
                     + v21*a3[6] + v22*a3[7] + v23*a3[8];
            float4 rr; rr.x = r0; rr.y = r1; rr.z = r2; rr.w = r3;
            *(float4*)(ob + (size_t)(g * 8 + cc) * (HO * WO)) = rr;
        }
    }
}

// ================== fallback: proven single fused kernel (R1) ==================
#define CCH 8
__global__ __launch_bounds__(128)
void la_fused(const float* __restrict__ guide,
              const float* __restrict__ value,
              const float* __restrict__ wconv,
              const float* __restrict__ bconv,
              float* __restrict__ out)
{
    __shared__ float s_wT[CH * 12];
    __shared__ float s_haloF[CCH * 110];

    const int tid = threadIdx.x;
    const int blk = blockIdx.x;
    const int wt = blk & 7;
    const int ht = (blk >> 3) & 7;
    const int b  = blk >> 6;

    for (int i = tid; i < KK * CH; i += 128) {
        int k = i >> 7;
        int c = i & 127;
        s_wT[c * 12 + k] = wconv[i];
    }

    const int tlwp = tid & 7;
    const int tho  = tid >> 3;
    const int ho = ht * 16 + tho;
    const int wo = wt * 16 + tlwp * 2;

    const float* gpix = guide + (((size_t)b * CH) * HO + ho) * WO + wo;

    float att0[KK], att1[KK];
    #pragma unroll
    for (int k = 0; k < KK; ++k) {
        float2 g = *(const float2*)(gpix + (size_t)k * (HO * WO));
        float bc = bconv[k];
        att0[k] = bc + g.x;
        att1[k] = bc + g.y;
    }
    __syncthreads();

    #pragma unroll 4
    for (int c = 0; c < CH; ++c) {
        float2 g = *(const float2*)(gpix + (size_t)c * (HO * WO));
        const float4* wt4 = (const float4*)&s_wT[c * 12];
        float4 wa = wt4[0];
        float4 wb = wt4[1];
        float w8 = s_wT[c * 12 + 8];
        att0[0] += g.x * wa.x;  att1[0] += g.y * wa.x;
        att0[1] += g.x * wa.y;  att1[1] += g.y * wa.y;
        att0[2] += g.x * wa.z;  att1[2] += g.y * wa.z;
        att0[3] += g.x * wa.w;  att1[3] += g.y * wa.w;
        att0[4] += g.x * wb.x;  att1[4] += g.y * wb.x;
        att0[5] += g.x * wb.y;  att1[5] += g.y * wb.y;
        att0[6] += g.x * wb.z;  att1[6] += g.y * wb.z;
        att0[7] += g.x * wb.w;  att1[7] += g.y * wb.w;
        att0[8] += g.x * w8;    att1[8] += g.y * w8;
    }

    float m0 = att0[0], m1 = att1[0];
    #pragma unroll
    for (int k = 1; k < KK; ++k) { m0 = fmaxf(m0, att0[k]); m1 = fmaxf(m1, att1[k]); }
    float s0 = 0.f, s1 = 0.f;
    #pragma unroll
    for (int k = 0; k < KK; ++k) {
        att0[k] = __expf(att0[k] - m0); s0 += att0[k];
        att1[k] = __expf(att1[k] - m1); s1 += att1[k];
    }
    float r0 = 1.0f / s0, r1 = 1.0f / s1;
    #pragma unroll
    for (int k = 0; k < KK; ++k) { att0[k] *= r0; att1[k] *= r1; }

    const int h0 = ht * 8 - 1;
    const int w0 = wt * 8 - 1;
    const int lh = tho >> 1;
    const float* vb = value + (size_t)b * CH * (HV * WV);
    float* ob = out + (((size_t)b * CH) * HO + ho) * WO + wo;

    for (int c0 = 0; c0 < CH; c0 += CCH) {
        __syncthreads();
        for (int i = tid; i < CCH * 100; i += 128) {
            int cc = i / 100;
            int r  = i - cc * 100;
            int hr = r / 10;
            int wr = r - hr * 10;
            int hh = min(max(h0 + hr, 0), HV - 1);
            int ww = min(max(w0 + wr, 0), WV - 1);
            s_haloF[cc * 110 + hr * 11 + wr] =
                vb[(size_t)(c0 + cc) * (HV * WV) + hh * WV + ww];
        }
        __syncthreads();
        #pragma unroll
        for (int cc = 0; cc < CCH; ++cc) {
            const float* hp = &s_haloF[cc * 110 + lh * 11 + tlwp];
            float v, q0, q1;
            v = hp[0];  q0  = v * att0[0]; q1  = v * att1[0];
            v = hp[1];  q0 += v * att0[1]; q1 += v * att1[1];
            v = hp[2];  q0 += v * att0[2]; q1 += v * att1[2];
            v = hp[11]; q0 += v * att0[3]; q1 += v * att1[3];
            v = hp[12]; q0 += v * att0[4]; q1 += v * att1[4];
            v = hp[13]; q0 += v * att0[5]; q1 += v * att1[5];
            v = hp[22]; q0 += v * att0[6]; q1 += v * att1[6];
            v = hp[23]; q0 += v * att0[7]; q1 += v * att1[7];
            v = hp[24]; q0 += v * att0[8]; q1 += v * att1[8];
            float2 rr; rr.x = q0; rr.y = q1;
            *(float2*)(ob + (size_t)(c0 + cc) * (HO * WO)) = rr;
        }
    }
}

extern "C" void kernel_launch(void* const* d_in, const int* in_sizes, int n_in,
                              void* d_out, int out_size, void* d_ws, size_t ws_size,
                              hipStream_t stream) {
    const float* guide = (const float*)d_in[0];
    const float* value = (const float*)d_in[1];
    const float* wconv = (const float*)d_in[2];
    const float* bconv = (const float*)d_in[3];
    float* outp = (float*)d_out;
    (void)in_sizes; (void)n_in; (void)out_size;

    const size_t att_bytes = (size_t)NB * KK * HO * WO * sizeof(float);  // 4.72 MB
    if (ws_size >= att_bytes) {
        float* attp = (float*)d_ws;
        la_att<<<dim3(512), dim3(256), 0, stream>>>(guide, wconv, bconv, attp);
        la_gather<<<dim3(2048), dim3(128), 0, stream>>>(value, attp, outp);
    } else {
        la_fused<<<dim3(NB * 8 * 8), dim3(128), 0, stream>>>(guide, value, wconv, bconv, outp);
    }
}